// Round 5
// baseline (8957.426 us; speedup 1.0000x reference)
//
#include <hip/hip_runtime.h>
#include <hip/hip_bf16.h>
#include <math.h>

typedef __hip_bfloat16 bf16;
typedef unsigned short us_t;

#define DM   512     // d_model (== INPUT)
#define DI   1024    // d_inner
#define NS   16      // d_state
#define DTR  32      // dt_rank
#define LSEQ 4096
#define NB   8
#define LC   128     // scan chunk length
#define NCH  32      // chunks per sequence
#define T    8       // sub-tile timesteps

#define MODE_BF16 0x11111111u
#define MODE_FP32 0x22222222u

__device__ __forceinline__ float us2f(unsigned int u) {
  return __uint_as_float((u & 0xffffu) << 16);
}
__device__ __forceinline__ float siluf(float x) { return x / (1.f + __expf(-x)); }
__device__ __forceinline__ float softplusf(float x) {
  return (x > 20.f) ? x : log1pf(__expf(x));
}

// --- dtype-generic element loads -------------------------------------------
template <typename TE> struct Elem;
template <> struct Elem<us_t> {
  static __device__ __forceinline__ float ld(const us_t* p) { return us2f(*p); }
  static __device__ __forceinline__ void ld8(const us_t* p, float* o) {
    uint4 v = *reinterpret_cast<const uint4*>(p);
    o[0] = us2f(v.x); o[1] = us2f(v.x >> 16);
    o[2] = us2f(v.y); o[3] = us2f(v.y >> 16);
    o[4] = us2f(v.z); o[5] = us2f(v.z >> 16);
    o[6] = us2f(v.w); o[7] = us2f(v.w >> 16);
  }
};
template <> struct Elem<float> {
  static __device__ __forceinline__ float ld(const float* p) { return *p; }
  static __device__ __forceinline__ void ld8(const float* p, float* o) {
    float4 a = *reinterpret_cast<const float4*>(p);
    float4 b = *reinterpret_cast<const float4*>(p + 4);
    o[0] = a.x; o[1] = a.y; o[2] = a.z; o[3] = a.w;
    o[4] = b.x; o[5] = b.y; o[6] = b.z; o[7] = b.w;
  }
};

// ---------------------------------------------------------------------------
// Dtype detector: interpret first 2048 bytes of x as fp32. True fp32 N(0,1)
// -> ~all plausible. True bf16 -> fp32-exponent byte ~252 -> |v|~1e37, none.
// ---------------------------------------------------------------------------
__global__ __launch_bounds__(256) void detect_k(const void* __restrict__ xv,
                                                unsigned* __restrict__ flag) {
  __shared__ int cnt;
  if (threadIdx.x == 0) cnt = 0;
  __syncthreads();
  const float* xf = (const float*)xv;
  float f = xf[threadIdx.x * 2];
  bool plaus = (f == 0.f) || (fabsf(f) > 1e-6f && fabsf(f) < 1e6f);
  if (plaus) atomicAdd(&cnt, 1);
  __syncthreads();
  if (threadIdx.x == 0) *flag = (cnt >= 192) ? MODE_FP32 : MODE_BF16;
}

// ---------------------------------------------------------------------------
// Fused chunk kernel. Block = (chunk c, batch b), 256 threads.
// Recomputes x->xp->xa->conv/silu->xdb->dt for its LC=128 steps in T=8 tiles.
// PHASE 1: writes sdt[b,c,d] = sum_t dt_t (1 MB).
// PHASE 2: scan partial S[d,n] in regs, recomputes C_last, contracts with
//          tail decay, atomicAdd into y[b,d].
// ---------------------------------------------------------------------------
template <int PHASE, typename TE>
__global__ __launch_bounds__(256, 1) void chunk_k(
    const TE* __restrict__ x, const TE* __restrict__ proj_w,
    const TE* __restrict__ proj_b, const TE* __restrict__ in_w,
    const TE* __restrict__ conv_w, const TE* __restrict__ conv_b,
    const TE* __restrict__ xproj_w, const TE* __restrict__ dt_w,
    const TE* __restrict__ dt_b, const TE* __restrict__ A_log,
    const TE* __restrict__ Dw, const unsigned* __restrict__ flag,
    float* __restrict__ sdtbuf, float* __restrict__ ybuf) {
  const unsigned want = (sizeof(TE) == 2) ? MODE_BF16 : MODE_FP32;
  if (*flag != want) return;

  __shared__ __align__(16) float xs[T][DM];    // 16 KB
  __shared__ __align__(16) float xps[T][DM];   // 16 KB
  __shared__ __align__(16) float xcs[T][DI];   // 32 KB
  __shared__ __align__(16) float xdbs[T][72];  // 2.25 KB
  __shared__ float cl[NS];

  const int tid = threadIdx.x;
  const int c = blockIdx.x, b = blockIdx.y;
  const int t0 = c * LC;
  const int d0 = tid * 4;   // channels d0..d0+3
  const int j0 = tid * 2;   // xp columns j0, j0+1

  float cw4[4][4], cb4[4], dtb4[4];
#pragma unroll
  for (int di = 0; di < 4; ++di) {
    const int d = d0 + di;
#pragma unroll
    for (int k = 0; k < 4; ++k) cw4[di][k] = Elem<TE>::ld(conv_w + d * 4 + k);
    cb4[di] = Elem<TE>::ld(conv_b + d);
    dtb4[di] = Elem<TE>::ld(dt_b + d);
  }

  float Ac[4][NS], S[4][NS];
  float sdt4[4] = {0.f, 0.f, 0.f, 0.f};
  if (PHASE == 2) {
#pragma unroll
    for (int di = 0; di < 4; ++di)
#pragma unroll
      for (int n = 0; n < NS; ++n) {
        Ac[di][n] = -__expf(Elem<TE>::ld(A_log + (d0 + di) * NS + n));
        S[di][n] = 0.f;
      }
  }

  auto fill_xs = [&](int grow, int rows) {
    const int tot = rows * (DM / 8);
    for (int i = tid; i < tot; i += 256) {
      const int r = i >> 6, kk = (i & 63) * 8;
      float tmp[8];
      Elem<TE>::ld8(x + ((size_t)grow + r) * DM + kk, tmp);
      *reinterpret_cast<float4*>(&xs[r][kk]) =
          make_float4(tmp[0], tmp[1], tmp[2], tmp[3]);
      *reinterpret_cast<float4*>(&xs[r][kk + 4]) =
          make_float4(tmp[4], tmp[5], tmp[6], tmp[7]);
    }
  };

  auto do_xp = [&](int rows) {
    float a0[T], a1[T];
#pragma unroll
    for (int t = 0; t < T; ++t) { a0[t] = 0.f; a1[t] = 0.f; }
    const TE* w0p = proj_w + (size_t)j0 * DM;
    const TE* w1p = w0p + DM;
    for (int k0 = 0; k0 < DM; k0 += 8) {
      float wA[8], wB[8];
      Elem<TE>::ld8(w0p + k0, wA);
      Elem<TE>::ld8(w1p + k0, wB);
      for (int t = 0; t < rows; ++t) {
        const float4 x0 = *reinterpret_cast<const float4*>(&xs[t][k0]);
        const float4 x1 = *reinterpret_cast<const float4*>(&xs[t][k0 + 4]);
        float xr[8] = {x0.x, x0.y, x0.z, x0.w, x1.x, x1.y, x1.z, x1.w};
#pragma unroll
        for (int q = 0; q < 8; ++q) {
          a0[t] = fmaf(xr[q], wA[q], a0[t]);
          a1[t] = fmaf(xr[q], wB[q], a1[t]);
        }
      }
    }
    const float pb0 = Elem<TE>::ld(proj_b + j0);
    const float pb1 = Elem<TE>::ld(proj_b + j0 + 1);
    for (int t = 0; t < rows; ++t) {
      xps[t][j0] = a0[t] + pb0;
      xps[t][j0 + 1] = a1[t] + pb1;
    }
  };

  auto xa_rows = [&](int d, int rows, float* a) {
    for (int t = 0; t < rows; ++t) a[t] = 0.f;
    const TE* wp = in_w + (size_t)d * DM;
    for (int k0 = 0; k0 < DM; k0 += 8) {
      float w[8];
      Elem<TE>::ld8(wp + k0, w);
      for (int t = 0; t < rows; ++t) {
        const float4 x0 = *reinterpret_cast<const float4*>(&xps[t][k0]);
        const float4 x1 = *reinterpret_cast<const float4*>(&xps[t][k0 + 4]);
        a[t] = fmaf(x0.x, w[0], a[t]); a[t] = fmaf(x0.y, w[1], a[t]);
        a[t] = fmaf(x0.z, w[2], a[t]); a[t] = fmaf(x0.w, w[3], a[t]);
        a[t] = fmaf(x1.x, w[4], a[t]); a[t] = fmaf(x1.y, w[5], a[t]);
        a[t] = fmaf(x1.z, w[6], a[t]); a[t] = fmaf(x1.w, w[7], a[t]);
      }
    }
  };

  // ---- PHASE 2 pre-stage: recompute C_last ----
  if (PHASE == 2) {
    fill_xs(b * LSEQ + LSEQ - 4, 4);
    __syncthreads();
    do_xp(4);
    __syncthreads();
#pragma unroll
    for (int di = 0; di < 4; ++di) {
      float a[T];
      xa_rows(d0 + di, 4, a);
      const float o = cb4[di] + cw4[di][0] * a[0] + cw4[di][1] * a[1] +
                      cw4[di][2] * a[2] + cw4[di][3] * a[3];
      xcs[0][d0 + di] = siluf(o);
    }
    __syncthreads();
    if (tid < NS) {
      const TE* wp = xproj_w + (size_t)(DTR + NS + tid) * DI;
      float s = 0.f;
      for (int k0 = 0; k0 < DI; k0 += 8) {
        float w[8];
        Elem<TE>::ld8(wp + k0, w);
        const float4 v0 = *reinterpret_cast<const float4*>(&xcs[0][k0]);
        const float4 v1 = *reinterpret_cast<const float4*>(&xcs[0][k0 + 4]);
        s = fmaf(v0.x, w[0], s); s = fmaf(v0.y, w[1], s);
        s = fmaf(v0.z, w[2], s); s = fmaf(v0.w, w[3], s);
        s = fmaf(v1.x, w[4], s); s = fmaf(v1.y, w[5], s);
        s = fmaf(v1.z, w[6], s); s = fmaf(v1.w, w[7], s);
      }
      cl[tid] = s;
    }
    __syncthreads();
  }

  // ---- pre-stage: conv carries (pre-conv xa at t0-3..t0-1) ----
  float cx[4][3];
#pragma unroll
  for (int di = 0; di < 4; ++di) cx[di][0] = cx[di][1] = cx[di][2] = 0.f;
  if (c > 0) {
    fill_xs(b * LSEQ + t0 - 3, 3);
    __syncthreads();
    do_xp(3);
    __syncthreads();
#pragma unroll
    for (int di = 0; di < 4; ++di) {
      float a[T];
      xa_rows(d0 + di, 3, a);
      cx[di][0] = a[0]; cx[di][1] = a[1]; cx[di][2] = a[2];
    }
  }

  // ---- main loop over sub-tiles ----
  for (int tt = 0; tt < LC; tt += T) {
    const int grow = b * LSEQ + t0 + tt;
    __syncthreads();
    fill_xs(grow, T);
    __syncthreads();
    do_xp(T);
    __syncthreads();
#pragma unroll
    for (int di = 0; di < 4; ++di) {
      float a[T];
      xa_rows(d0 + di, T, a);
#pragma unroll
      for (int t = 0; t < T; ++t) {
        const float o = cb4[di] + cw4[di][0] * cx[di][0] +
                        cw4[di][1] * cx[di][1] + cw4[di][2] * cx[di][2] +
                        cw4[di][3] * a[t];
        cx[di][0] = cx[di][1]; cx[di][1] = cx[di][2]; cx[di][2] = a[t];
        xcs[t][d0 + di] = siluf(o);
      }
    }
    __syncthreads();
    {
      const int t = tid >> 5;
      const int n0 = (tid & 31) * 2;
      const TE* wp0 = xproj_w + (size_t)n0 * DI;
      const TE* wp1 = wp0 + DI;
      float s0 = 0.f, s1 = 0.f;
      for (int k0 = 0; k0 < DI; k0 += 8) {
        float wa[8], wb[8];
        Elem<TE>::ld8(wp0 + k0, wa);
        Elem<TE>::ld8(wp1 + k0, wb);
        const float4 v0 = *reinterpret_cast<const float4*>(&xcs[t][k0]);
        const float4 v1 = *reinterpret_cast<const float4*>(&xcs[t][k0 + 4]);
        s0 = fmaf(v0.x, wa[0], s0); s0 = fmaf(v0.y, wa[1], s0);
        s0 = fmaf(v0.z, wa[2], s0); s0 = fmaf(v0.w, wa[3], s0);
        s0 = fmaf(v1.x, wa[4], s0); s0 = fmaf(v1.y, wa[5], s0);
        s0 = fmaf(v1.z, wa[6], s0); s0 = fmaf(v1.w, wa[7], s0);
        s1 = fmaf(v0.x, wb[0], s1); s1 = fmaf(v0.y, wb[1], s1);
        s1 = fmaf(v0.z, wb[2], s1); s1 = fmaf(v0.w, wb[3], s1);
        s1 = fmaf(v1.x, wb[4], s1); s1 = fmaf(v1.y, wb[5], s1);
        s1 = fmaf(v1.z, wb[6], s1); s1 = fmaf(v1.w, wb[7], s1);
      }
      xdbs[t][n0] = s0; xdbs[t][n0 + 1] = s1;
    }
    __syncthreads();
#pragma unroll
    for (int di = 0; di < 4; ++di) {
      const int d = d0 + di;
      float dtw[DTR];
#pragma unroll
      for (int k0 = 0; k0 < DTR; k0 += 8) Elem<TE>::ld8(dt_w + (size_t)d * DTR + k0, dtw + k0);
#pragma unroll
      for (int t = 0; t < T; ++t) {
        float raw = dtb4[di];
#pragma unroll
        for (int r = 0; r < DTR; ++r) raw = fmaf(xdbs[t][r], dtw[r], raw);
        const float dtv = softplusf(raw);
        sdt4[di] += dtv;
        if (PHASE == 2) {
          const float w = dtv * xcs[t][d];
#pragma unroll
          for (int n = 0; n < NS; ++n)
            S[di][n] = fmaf(S[di][n], __expf(dtv * Ac[di][n]),
                            w * xdbs[t][DTR + n]);
        }
      }
    }
  }

  if (PHASE == 1) {
#pragma unroll
    for (int di = 0; di < 4; ++di)
      sdtbuf[((size_t)b * NCH + c) * DI + d0 + di] = sdt4[di];
  } else {
#pragma unroll
    for (int di = 0; di < 4; ++di) {
      const int d = d0 + di;
      float tail = 0.f;
      for (int cc = c + 1; cc < NCH; ++cc)
        tail += sdtbuf[((size_t)b * NCH + cc) * DI + d];
      float contrib = 0.f;
#pragma unroll
      for (int n = 0; n < NS; ++n)
        contrib += S[di][n] * cl[n] * __expf(Ac[di][n] * tail);
      if (c == NCH - 1) contrib += xcs[T - 1][d] * Elem<TE>::ld(Dw + d);
      atomicAdd(ybuf + (size_t)b * DI + d, contrib);
    }
  }
}

// ---------------------------------------------------------------------------
template <typename TE>
__device__ __forceinline__ float dotw(const float* lds, const TE* wrow, int n) {
  float s = 0.f;
  for (int k = 0; k < n; k += 8) {
    float w[8];
    Elem<TE>::ld8(wrow + k, w);
#pragma unroll
    for (int q = 0; q < 8; ++q) s = fmaf(lds[k + q], w[q], s);
  }
  return s;
}

// Tail: all last-token-only work (fwd gate, entire bwd branch, out/fusion/LN).
template <typename TE>
__global__ __launch_bounds__(512) void tail_k(
    const TE* __restrict__ x, const TE* __restrict__ proj_w,
    const TE* __restrict__ proj_b, const float* __restrict__ ybuf,
    const TE* in_w_f, const TE* out_w_f, const TE* in_w_b,
    const TE* conv_w_b, const TE* conv_b_b, const TE* xproj_w_b,
    const TE* dt_w_b, const TE* dt_b_b, const TE* D_b,
    const TE* out_w_b, const TE* fusion_w, const TE* fusion_b,
    const TE* ln_g, const TE* ln_b, const unsigned* __restrict__ flag,
    void* __restrict__ outv) {
  const unsigned want = (sizeof(TE) == 2) ? MODE_BF16 : MODE_FP32;
  if (*flag != want) return;

  __shared__ float xls[DM];
  __shared__ float xpL[DM];
  __shared__ float xcb[DI];
  __shared__ float zb[DI];
  __shared__ float zf[DI];
  __shared__ float gf[DI];
  __shared__ float gb[DI];
  __shared__ float cat[DI];
  __shared__ float xdbb[64];
  __shared__ float red[DM];
  __shared__ float mu_s, var_s;
  const int b = blockIdx.x, t = threadIdx.x;

  xls[t] = Elem<TE>::ld(x + ((size_t)b * LSEQ + (LSEQ - 1)) * DM + t);
  __syncthreads();
  xpL[t] = Elem<TE>::ld(proj_b + t) + dotw(xls, proj_w + (size_t)t * DM, DM);
  __syncthreads();

  for (int q = 0; q < 4; ++q) {
    int i = q * 512 + t;
    float s = dotw(xpL, in_w_b + (size_t)i * DM, DM);
    if (i < DI) {
      float v = s * Elem<TE>::ld(conv_w_b + i * 4 + 3) + Elem<TE>::ld(conv_b_b + i);
      xcb[i] = siluf(v);
    } else {
      zb[i - DI] = s;
    }
  }
  for (int q = 0; q < 2; ++q) {
    int d = q * 512 + t;
    zf[d] = dotw(xpL, in_w_f + (size_t)(DI + d) * DM, DM);
  }
  __syncthreads();

  if (t < 64) xdbb[t] = dotw(xcb, xproj_w_b + (size_t)t * DI, DI);
  __syncthreads();

  float bc = 0.f;
#pragma unroll
  for (int n = 0; n < NS; ++n) bc += xdbb[DTR + n] * xdbb[DTR + NS + n];

  for (int q = 0; q < 2; ++q) {
    int d = q * 512 + t;
    float raw = Elem<TE>::ld(dt_b_b + d);
    float dtw8[DTR];
#pragma unroll
    for (int k0 = 0; k0 < DTR; k0 += 8) Elem<TE>::ld8(dt_w_b + (size_t)d * DTR + k0, dtw8 + k0);
#pragma unroll
    for (int r = 0; r < DTR; ++r) raw = fmaf(xdbb[r], dtw8[r], raw);
    float dtv = softplusf(raw);
    float yb = dtv * xcb[d] * bc + xcb[d] * Elem<TE>::ld(D_b + d);
    gb[d] = yb * siluf(zb[d]);
    gf[d] = ybuf[(size_t)b * DI + d] * siluf(zf[d]);
  }
  __syncthreads();

  cat[t] = dotw(gf, out_w_f + (size_t)t * DI, DI);
  cat[DM + t] = dotw(gb, out_w_b + (size_t)t * DI, DI);
  __syncthreads();

  float rv = Elem<TE>::ld(fusion_b + t) + dotw(cat, fusion_w + (size_t)t * DI, DI);

  red[t] = rv;
  __syncthreads();
  for (int s = 256; s > 0; s >>= 1) {
    if (t < s) red[t] += red[t + s];
    __syncthreads();
  }
  if (t == 0) mu_s = red[0] * (1.f / DM);
  __syncthreads();
  float dv = rv - mu_s;
  red[t] = dv * dv;
  __syncthreads();
  for (int s = 256; s > 0; s >>= 1) {
    if (t < s) red[t] += red[t + s];
    __syncthreads();
  }
  if (t == 0) var_s = red[0] * (1.f / DM);
  __syncthreads();
  float val = dv * rsqrtf(var_s + 1e-5f) * Elem<TE>::ld(ln_g + t) +
              Elem<TE>::ld(ln_b + t);
  if (sizeof(TE) == 2)
    ((bf16*)outv)[(size_t)b * DM + t] = __float2bfloat16(val);
  else
    ((float*)outv)[(size_t)b * DM + t] = val;
}

// ---------------------------------------------------------------------------
extern "C" void kernel_launch(void* const* d_in, const int* in_sizes, int n_in,
                              void* d_out, int out_size, void* d_ws,
                              size_t ws_size, hipStream_t stream) {
  (void)in_sizes; (void)n_in; (void)out_size; (void)ws_size;

  char* base = (char*)d_ws;
  unsigned* flag = (unsigned*)base;                               // 4 B
  float* sdt = (float*)(base + 256);                              // 1 MB
  float* y   = (float*)(base + 256 + (size_t)NB * NCH * DI * 4);  // 32 KB

  hipMemsetAsync(y, 0, (size_t)NB * DI * 4, stream);
  detect_k<<<dim3(1), dim3(256), 0, stream>>>(d_in[0], flag);

  dim3 g(NCH, NB), blk(256);

#define CHUNK_ARGS(TY)                                                        \
  (const TY*)d_in[0], (const TY*)d_in[1], (const TY*)d_in[2],                 \
  (const TY*)d_in[3], (const TY*)d_in[4], (const TY*)d_in[5],                 \
  (const TY*)d_in[6], (const TY*)d_in[7], (const TY*)d_in[8],                 \
  (const TY*)d_in[9], (const TY*)d_in[10], flag, sdt, y

  chunk_k<1, us_t><<<g, blk, 0, stream>>>(CHUNK_ARGS(us_t));
  chunk_k<1, float><<<g, blk, 0, stream>>>(CHUNK_ARGS(float));
  chunk_k<2, us_t><<<g, blk, 0, stream>>>(CHUNK_ARGS(us_t));
  chunk_k<2, float><<<g, blk, 0, stream>>>(CHUNK_ARGS(float));

#define TAIL_ARGS(TY)                                                         \
  (const TY*)d_in[0], (const TY*)d_in[1], (const TY*)d_in[2], y,              \
  (const TY*)d_in[3], (const TY*)d_in[11], (const TY*)d_in[12],               \
  (const TY*)d_in[13], (const TY*)d_in[14], (const TY*)d_in[15],              \
  (const TY*)d_in[16], (const TY*)d_in[17], (const TY*)d_in[19],              \
  (const TY*)d_in[20], (const TY*)d_in[21], (const TY*)d_in[22],              \
  (const TY*)d_in[23], (const TY*)d_in[24], flag, d_out

  tail_k<us_t><<<dim3(NB), dim3(512), 0, stream>>>(TAIL_ARGS(us_t));
  tail_k<float><<<dim3(NB), dim3(512), 0, stream>>>(TAIL_ARGS(float));
}

// Round 6
// 4940.829 us; speedup vs baseline: 1.8129x; 1.8129x over previous
//
#include <hip/hip_runtime.h>
#include <hip/hip_bf16.h>
#include <math.h>

typedef __hip_bfloat16 bf16;

#define DM   512     // d_model (== INPUT)
#define DI   1024    // d_inner
#define NS   16      // d_state
#define DTR  32      // dt_rank
#define LSEQ 4096
#define NB   8
#define T    8       // sub-tile timesteps
#define THR  512     // threads per chunk block

__device__ __forceinline__ float siluf(float x) { return x / (1.f + __expf(-x)); }
__device__ __forceinline__ float softplusf(float x) {
  return (x > 20.f) ? x : log1pf(__expf(x));
}

// ---------------------------------------------------------------------------
// Fused chunk kernel. Block = (chunk c, batch b), 512 threads, 2 ch/thread.
// Recomputes x->xp->xa->conv/silu->xdb->dt for its LCr steps in T=8 tiles.
// MODE 0 (single): store sdt + scan partial S to ws; fold_k combines.
// MODE 1 (phase1): store sdt only (+ C_last/xc_last from last chunk).
// MODE 2 (phase2): S in regs, contract with tail decay, atomicAdd into y.
// ---------------------------------------------------------------------------
template <int MODE>
__global__ __launch_bounds__(THR, 4) void chunk_k(
    const float* __restrict__ x, const float* __restrict__ proj_w,
    const float* __restrict__ proj_b, const float* __restrict__ in_w,
    const float* __restrict__ conv_w, const float* __restrict__ conv_b,
    const float* __restrict__ xproj_w, const float* __restrict__ dt_w,
    const float* __restrict__ dt_b, const float* __restrict__ A_log,
    const float* __restrict__ Dw, float* __restrict__ sdtbuf,
    float* __restrict__ Sbuf, float* __restrict__ clb,
    float* __restrict__ xclast, float* __restrict__ ybuf,
    int NCHR, int LCr) {
  __shared__ __align__(16) float xs[T][DM];    // 16 KB
  __shared__ __align__(16) float xps[T][DM];   // 16 KB
  __shared__ __align__(16) float xcs[T][DI];   // 32 KB
  __shared__ __align__(16) float xdbs[T][72];  // 2.25 KB

  const int tid = threadIdx.x;
  const int c = blockIdx.x, b = blockIdx.y;
  const int t0 = c * LCr;
  const int d0 = tid * 2;   // this thread owns channels d0, d0+1
  const int j0 = tid;       // and xp column j0

  float cw[2][4], cb2[2], dtb2[2];
#pragma unroll
  for (int di = 0; di < 2; ++di) {
    const int d = d0 + di;
#pragma unroll
    for (int k = 0; k < 4; ++k) cw[di][k] = conv_w[d * 4 + k];
    cb2[di] = conv_b[d];
    dtb2[di] = dt_b[d];
  }

  float Ac[2][NS], S[2][NS];
  float sdt2[2] = {0.f, 0.f};
  if (MODE != 1) {
#pragma unroll
    for (int di = 0; di < 2; ++di)
#pragma unroll
      for (int n = 0; n < NS; ++n) {
        Ac[di][n] = -__expf(A_log[(d0 + di) * NS + n]);
        S[di][n] = 0.f;
      }
  }

  auto fill_xs = [&](int grow, int rows) {
    const int tot = rows * (DM / 4);
    for (int i = tid; i < tot; i += THR) {
      const int r = i >> 7, kk = (i & 127) * 4;
      *reinterpret_cast<float4*>(&xs[r][kk]) =
          *reinterpret_cast<const float4*>(x + ((size_t)grow + r) * DM + kk);
    }
  };

  auto do_xp = [&](int rows) {
    float a0[T];
#pragma unroll
    for (int t = 0; t < T; ++t) a0[t] = 0.f;
    const float* wr = proj_w + (size_t)j0 * DM;
    for (int k0 = 0; k0 < DM; k0 += 8) {
      const float4 w0 = *reinterpret_cast<const float4*>(wr + k0);
      const float4 w1 = *reinterpret_cast<const float4*>(wr + k0 + 4);
      for (int t = 0; t < rows; ++t) {
        const float4 x0 = *reinterpret_cast<const float4*>(&xs[t][k0]);
        const float4 x1 = *reinterpret_cast<const float4*>(&xs[t][k0 + 4]);
        a0[t] = fmaf(x0.x, w0.x, a0[t]); a0[t] = fmaf(x0.y, w0.y, a0[t]);
        a0[t] = fmaf(x0.z, w0.z, a0[t]); a0[t] = fmaf(x0.w, w0.w, a0[t]);
        a0[t] = fmaf(x1.x, w1.x, a0[t]); a0[t] = fmaf(x1.y, w1.y, a0[t]);
        a0[t] = fmaf(x1.z, w1.z, a0[t]); a0[t] = fmaf(x1.w, w1.w, a0[t]);
      }
    }
    const float pb = proj_b[j0];
    for (int t = 0; t < rows; ++t) xps[t][j0] = a0[t] + pb;
  };

  auto xa2 = [&](int rows, float (*a)[T]) {
    for (int t = 0; t < rows; ++t) { a[0][t] = 0.f; a[1][t] = 0.f; }
    const float* w0p = in_w + (size_t)d0 * DM;
    const float* w1p = w0p + DM;
    for (int k0 = 0; k0 < DM; k0 += 4) {
      const float4 wa = *reinterpret_cast<const float4*>(w0p + k0);
      const float4 wb = *reinterpret_cast<const float4*>(w1p + k0);
      for (int t = 0; t < rows; ++t) {
        const float4 xv = *reinterpret_cast<const float4*>(&xps[t][k0]);
        a[0][t] = fmaf(xv.x, wa.x, a[0][t]); a[0][t] = fmaf(xv.y, wa.y, a[0][t]);
        a[0][t] = fmaf(xv.z, wa.z, a[0][t]); a[0][t] = fmaf(xv.w, wa.w, a[0][t]);
        a[1][t] = fmaf(xv.x, wb.x, a[1][t]); a[1][t] = fmaf(xv.y, wb.y, a[1][t]);
        a[1][t] = fmaf(xv.z, wb.z, a[1][t]); a[1][t] = fmaf(xv.w, wb.w, a[1][t]);
      }
    }
  };

  // ---- pre-stage: conv carries (pre-conv xa at t0-3..t0-1) ----
  float cx[2][3];
#pragma unroll
  for (int di = 0; di < 2; ++di) cx[di][0] = cx[di][1] = cx[di][2] = 0.f;
  if (c > 0) {
    fill_xs(b * LSEQ + t0 - 3, 3);
    __syncthreads();
    do_xp(3);
    __syncthreads();
    float a[2][T];
    xa2(3, a);
#pragma unroll
    for (int di = 0; di < 2; ++di) {
      cx[di][0] = a[di][0]; cx[di][1] = a[di][1]; cx[di][2] = a[di][2];
    }
  }

  // ---- main loop over sub-tiles ----
  for (int tt = 0; tt < LCr; tt += T) {
    const int grow = b * LSEQ + t0 + tt;
    __syncthreads();
    fill_xs(grow, T);
    __syncthreads();
    do_xp(T);
    __syncthreads();
    {
      float a[2][T];
      xa2(T, a);
#pragma unroll
      for (int di = 0; di < 2; ++di) {
#pragma unroll
        for (int t = 0; t < T; ++t) {
          const float o = cb2[di] + cw[di][0] * cx[di][0] +
                          cw[di][1] * cx[di][1] + cw[di][2] * cx[di][2] +
                          cw[di][3] * a[di][t];
          cx[di][0] = cx[di][1]; cx[di][1] = cx[di][2]; cx[di][2] = a[di][t];
          xcs[t][d0 + di] = siluf(o);
        }
      }
    }
    __syncthreads();
    // xdb = xc @ xproj_w.T : one output per thread (t = tid>>6, n = tid&63)
    {
      const int t = tid >> 6;
      const int n0 = tid & 63;
      const float* wp = xproj_w + (size_t)n0 * DI;
      float s = 0.f;
      for (int k0 = 0; k0 < DI; k0 += 8) {
        const float4 w0 = *reinterpret_cast<const float4*>(wp + k0);
        const float4 w1 = *reinterpret_cast<const float4*>(wp + k0 + 4);
        const float4 v0 = *reinterpret_cast<const float4*>(&xcs[t][k0]);
        const float4 v1 = *reinterpret_cast<const float4*>(&xcs[t][k0 + 4]);
        s = fmaf(v0.x, w0.x, s); s = fmaf(v0.y, w0.y, s);
        s = fmaf(v0.z, w0.z, s); s = fmaf(v0.w, w0.w, s);
        s = fmaf(v1.x, w1.x, s); s = fmaf(v1.y, w1.y, s);
        s = fmaf(v1.z, w1.z, s); s = fmaf(v1.w, w1.w, s);
      }
      xdbs[t][n0] = s;
    }
    __syncthreads();
    // dt + scan partial update (2 channels per thread)
    {
      float raw0[T], raw1[T];
#pragma unroll
      for (int t = 0; t < T; ++t) { raw0[t] = dtb2[0]; raw1[t] = dtb2[1]; }
      const float* dw0 = dt_w + (size_t)d0 * DTR;
      const float* dw1 = dw0 + DTR;
#pragma unroll
      for (int r0 = 0; r0 < DTR; r0 += 8) {
        const float4 u0 = *reinterpret_cast<const float4*>(dw0 + r0);
        const float4 u1 = *reinterpret_cast<const float4*>(dw0 + r0 + 4);
        const float4 v0 = *reinterpret_cast<const float4*>(dw1 + r0);
        const float4 v1 = *reinterpret_cast<const float4*>(dw1 + r0 + 4);
#pragma unroll
        for (int t = 0; t < T; ++t) {
          const float4 b0 = *reinterpret_cast<const float4*>(&xdbs[t][r0]);
          const float4 b1 = *reinterpret_cast<const float4*>(&xdbs[t][r0 + 4]);
          raw0[t] = fmaf(b0.x, u0.x, raw0[t]); raw0[t] = fmaf(b0.y, u0.y, raw0[t]);
          raw0[t] = fmaf(b0.z, u0.z, raw0[t]); raw0[t] = fmaf(b0.w, u0.w, raw0[t]);
          raw0[t] = fmaf(b1.x, u1.x, raw0[t]); raw0[t] = fmaf(b1.y, u1.y, raw0[t]);
          raw0[t] = fmaf(b1.z, u1.z, raw0[t]); raw0[t] = fmaf(b1.w, u1.w, raw0[t]);
          raw1[t] = fmaf(b0.x, v0.x, raw1[t]); raw1[t] = fmaf(b0.y, v0.y, raw1[t]);
          raw1[t] = fmaf(b0.z, v0.z, raw1[t]); raw1[t] = fmaf(b0.w, v0.w, raw1[t]);
          raw1[t] = fmaf(b1.x, v1.x, raw1[t]); raw1[t] = fmaf(b1.y, v1.y, raw1[t]);
          raw1[t] = fmaf(b1.z, v1.z, raw1[t]); raw1[t] = fmaf(b1.w, v1.w, raw1[t]);
        }
      }
#pragma unroll
      for (int t = 0; t < T; ++t) {
        const float dtv0 = softplusf(raw0[t]);
        const float dtv1 = softplusf(raw1[t]);
        sdt2[0] += dtv0;
        sdt2[1] += dtv1;
        if (MODE != 1) {
          const float w0 = dtv0 * xcs[t][d0];
          const float w1 = dtv1 * xcs[t][d0 + 1];
#pragma unroll
          for (int n = 0; n < NS; ++n) {
            const float Bn = xdbs[t][DTR + n];
            S[0][n] = fmaf(S[0][n], __expf(dtv0 * Ac[0][n]), w0 * Bn);
            S[1][n] = fmaf(S[1][n], __expf(dtv1 * Ac[1][n]), w1 * Bn);
          }
        }
      }
    }
  }

  // ---- epilogue ----
  const size_t sidx = ((size_t)b * NCHR + c) * DI + d0;
  if (MODE == 0) {
    sdtbuf[sidx] = sdt2[0];
    sdtbuf[sidx + 1] = sdt2[1];
#pragma unroll
    for (int n = 0; n < NS; ++n) {
      float2 v; v.x = S[0][n]; v.y = S[1][n];
      *reinterpret_cast<float2*>(
          Sbuf + (((size_t)b * NCHR + c) * NS + n) * DI + d0) = v;
    }
    if (c == NCHR - 1) {
      xclast[(size_t)b * DI + d0] = xcs[T - 1][d0];
      xclast[(size_t)b * DI + d0 + 1] = xcs[T - 1][d0 + 1];
      if (tid < NS) clb[b * NS + tid] = xdbs[T - 1][DTR + NS + tid];
    }
  } else if (MODE == 1) {
    sdtbuf[sidx] = sdt2[0];
    sdtbuf[sidx + 1] = sdt2[1];
    if (c == NCHR - 1) {
      xclast[(size_t)b * DI + d0] = xcs[T - 1][d0];
      xclast[(size_t)b * DI + d0 + 1] = xcs[T - 1][d0 + 1];
      if (tid < NS) clb[b * NS + tid] = xdbs[T - 1][DTR + NS + tid];
    }
  } else {
    float tail0 = 0.f, tail1 = 0.f;
    for (int cc = c + 1; cc < NCHR; ++cc) {
      tail0 += sdtbuf[((size_t)b * NCHR + cc) * DI + d0];
      tail1 += sdtbuf[((size_t)b * NCHR + cc) * DI + d0 + 1];
    }
    float c0 = 0.f, c1 = 0.f;
#pragma unroll
    for (int n = 0; n < NS; ++n) {
      const float cn = clb[b * NS + n];
      c0 += S[0][n] * cn * __expf(Ac[0][n] * tail0);
      c1 += S[1][n] * cn * __expf(Ac[1][n] * tail1);
    }
    if (c == NCHR - 1) {
      c0 += xcs[T - 1][d0] * Dw[d0];
      c1 += xcs[T - 1][d0 + 1] * Dw[d0 + 1];
    }
    atomicAdd(ybuf + (size_t)b * DI + d0, c0);
    atomicAdd(ybuf + (size_t)b * DI + d0 + 1, c1);
  }
}

// ---------------------------------------------------------------------------
// Fold chunk partials (single-phase path): h = fold over chunks, y = h.C + uD
// ---------------------------------------------------------------------------
__global__ __launch_bounds__(256) void fold_k(
    const float* __restrict__ sdt, const float* __restrict__ Sb,
    const float* __restrict__ A_log, const float* __restrict__ clb,
    const float* __restrict__ xclast, const float* __restrict__ Dw,
    float* __restrict__ y, int NCHR) {
  const int tid = blockIdx.x * 256 + threadIdx.x;
  const int b = tid >> 10, d = tid & (DI - 1);
  float Ac[NS], h[NS];
#pragma unroll
  for (int n = 0; n < NS; ++n) {
    Ac[n] = -__expf(A_log[d * NS + n]);
    h[n] = 0.f;
  }
  for (int c = 0; c < NCHR; ++c) {
    const float s = sdt[((size_t)b * NCHR + c) * DI + d];
#pragma unroll
    for (int n = 0; n < NS; ++n)
      h[n] = fmaf(h[n], __expf(Ac[n] * s),
                  Sb[(((size_t)b * NCHR + c) * NS + n) * DI + d]);
  }
  float acc = 0.f;
#pragma unroll
  for (int n = 0; n < NS; ++n) acc += h[n] * clb[b * NS + n];
  y[(size_t)b * DI + d] = acc + xclast[(size_t)b * DI + d] * Dw[d];
}

// ---------------------------------------------------------------------------
__device__ __forceinline__ float dotf(const float* lds, const float* w, int n) {
  float s = 0.f;
#pragma unroll 4
  for (int k = 0; k < n; k += 4) {
    const float4 wv = *reinterpret_cast<const float4*>(w + k);
    s = fmaf(lds[k], wv.x, s);
    s = fmaf(lds[k + 1], wv.y, s);
    s = fmaf(lds[k + 2], wv.z, s);
    s = fmaf(lds[k + 3], wv.w, s);
  }
  return s;
}

// Tail: all last-token-only work (fwd gate, entire bwd branch, out/fusion/LN).
__global__ __launch_bounds__(512) void tail_k(
    const float* __restrict__ x, const float* __restrict__ proj_w,
    const float* __restrict__ proj_b, const float* __restrict__ ybuf,
    const float* in_w_f, const float* out_w_f, const float* in_w_b,
    const float* conv_w_b, const float* conv_b_b, const float* xproj_w_b,
    const float* dt_w_b, const float* dt_b_b, const float* D_b,
    const float* out_w_b, const float* fusion_w, const float* fusion_b,
    const float* ln_g, const float* ln_b, float* __restrict__ out) {
  __shared__ float xls[DM];
  __shared__ float xpL[DM];
  __shared__ float xcb[DI];
  __shared__ float zb[DI];
  __shared__ float zf[DI];
  __shared__ float gf[DI];
  __shared__ float gb[DI];
  __shared__ float cat[DI];
  __shared__ float xdbb[64];
  __shared__ float red[DM];
  __shared__ float mu_s, var_s;
  const int b = blockIdx.x, t = threadIdx.x;

  xls[t] = x[((size_t)b * LSEQ + (LSEQ - 1)) * DM + t];
  __syncthreads();
  xpL[t] = proj_b[t] + dotf(xls, proj_w + (size_t)t * DM, DM);
  __syncthreads();

  for (int q = 0; q < 4; ++q) {
    int i = q * 512 + t;
    float s = dotf(xpL, in_w_b + (size_t)i * DM, DM);
    if (i < DI) {
      xcb[i] = siluf(s * conv_w_b[i * 4 + 3] + conv_b_b[i]);
    } else {
      zb[i - DI] = s;
    }
  }
  for (int q = 0; q < 2; ++q) {
    int d = q * 512 + t;
    zf[d] = dotf(xpL, in_w_f + (size_t)(DI + d) * DM, DM);
  }
  __syncthreads();

  if (t < 64) xdbb[t] = dotf(xcb, xproj_w_b + (size_t)t * DI, DI);
  __syncthreads();

  float bc = 0.f;
#pragma unroll
  for (int n = 0; n < NS; ++n) bc += xdbb[DTR + n] * xdbb[DTR + NS + n];

  for (int q = 0; q < 2; ++q) {
    int d = q * 512 + t;
    float raw = dt_b_b[d];
    const float* wr = dt_w_b + (size_t)d * DTR;
#pragma unroll
    for (int r = 0; r < DTR; ++r) raw = fmaf(xdbb[r], wr[r], raw);
    float dtv = softplusf(raw);
    float yb = dtv * xcb[d] * bc + xcb[d] * D_b[d];
    gb[d] = yb * siluf(zb[d]);
    gf[d] = ybuf[(size_t)b * DI + d] * siluf(zf[d]);
  }
  __syncthreads();

  cat[t] = dotf(gf, out_w_f + (size_t)t * DI, DI);
  cat[DM + t] = dotf(gb, out_w_b + (size_t)t * DI, DI);
  __syncthreads();

  float rv = fusion_b[t] + dotf(cat, fusion_w + (size_t)t * DI, DI);

  red[t] = rv;
  __syncthreads();
  for (int s = 256; s > 0; s >>= 1) {
    if (t < s) red[t] += red[t + s];
    __syncthreads();
  }
  if (t == 0) mu_s = red[0] * (1.f / DM);
  __syncthreads();
  float dv = rv - mu_s;
  red[t] = dv * dv;
  __syncthreads();
  for (int s = 256; s > 0; s >>= 1) {
    if (t < s) red[t] += red[t + s];
    __syncthreads();
  }
  if (t == 0) var_s = red[0] * (1.f / DM);
  __syncthreads();
  out[(size_t)b * DM + t] = dv * rsqrtf(var_s + 1e-5f) * ln_g[t] + ln_b[t];
}

// ---------------------------------------------------------------------------
static size_t plan_need(int nch, bool sgl, size_t* offs) {
  size_t o = 0;
  int idx = 0;
  auto al = [&](size_t n) {
    size_t q = (o + 255) & ~(size_t)255;
    o = q + n;
    if (offs) offs[idx] = q;
    ++idx;
    return q;
  };
  al((size_t)NB * DI * 4);               // 0: y
  al((size_t)NB * nch * DI * 4);         // 1: sdt
  al((size_t)NB * NS * 4);               // 2: clb
  al((size_t)NB * DI * 4);               // 3: xclast
  if (sgl) al((size_t)NB * nch * NS * DI * 4);  // 4: Sb
  return o;
}

extern "C" void kernel_launch(void* const* d_in, const int* in_sizes, int n_in,
                              void* d_out, int out_size, void* d_ws,
                              size_t ws_size, hipStream_t stream) {
  (void)in_sizes; (void)n_in; (void)out_size;
  const float* x        = (const float*)d_in[0];
  const float* proj_w   = (const float*)d_in[1];
  const float* proj_b   = (const float*)d_in[2];
  const float* in_w_f   = (const float*)d_in[3];
  const float* conv_w_f = (const float*)d_in[4];
  const float* conv_b_f = (const float*)d_in[5];
  const float* xproj_w_f= (const float*)d_in[6];
  const float* dt_w_f   = (const float*)d_in[7];
  const float* dt_b_f   = (const float*)d_in[8];
  const float* A_log_f  = (const float*)d_in[9];
  const float* D_f      = (const float*)d_in[10];
  const float* out_w_f  = (const float*)d_in[11];
  const float* in_w_b   = (const float*)d_in[12];
  const float* conv_w_b = (const float*)d_in[13];
  const float* conv_b_b = (const float*)d_in[14];
  const float* xproj_w_b= (const float*)d_in[15];
  const float* dt_w_b   = (const float*)d_in[16];
  const float* dt_b_b   = (const float*)d_in[17];
  // d_in[18] = A_log_b unused (bwd branch only needs t=0, where h0 = 0)
  const float* D_b      = (const float*)d_in[19];
  const float* out_w_b  = (const float*)d_in[20];
  const float* fusion_w = (const float*)d_in[21];
  const float* fusion_b = (const float*)d_in[22];
  const float* ln_g     = (const float*)d_in[23];
  const float* ln_b     = (const float*)d_in[24];

  // Plan ladder (host-constant wrt ws_size -> graph-safe). R5 proved >=1.1MB.
  int NCHR;
  bool single;
  if (ws_size >= plan_need(64, true, nullptr)) { NCHR = 64; single = true; }
  else if (ws_size >= plan_need(32, true, nullptr)) { NCHR = 32; single = true; }
  else if (ws_size >= plan_need(64, false, nullptr)) { NCHR = 64; single = false; }
  else { NCHR = 32; single = false; }
  const int LCr = LSEQ / NCHR;

  size_t offs[5] = {0, 0, 0, 0, 0};
  plan_need(NCHR, single, offs);
  char* base = (char*)d_ws;
  float* y      = (float*)(base + offs[0]);
  float* sdt    = (float*)(base + offs[1]);
  float* clb    = (float*)(base + offs[2]);
  float* xclast = (float*)(base + offs[3]);
  float* Sb     = single ? (float*)(base + offs[4]) : nullptr;

  hipMemsetAsync(y, 0, (size_t)NB * DI * 4, stream);

  dim3 g(NCHR, NB), blk(THR);
  if (single) {
    chunk_k<0><<<g, blk, 0, stream>>>(
        x, proj_w, proj_b, in_w_f, conv_w_f, conv_b_f, xproj_w_f, dt_w_f,
        dt_b_f, A_log_f, D_f, sdt, Sb, clb, xclast, y, NCHR, LCr);
    fold_k<<<dim3((NB * DI) / 256), dim3(256), 0, stream>>>(
        sdt, Sb, A_log_f, clb, xclast, D_f, y, NCHR);
  } else {
    chunk_k<1><<<g, blk, 0, stream>>>(
        x, proj_w, proj_b, in_w_f, conv_w_f, conv_b_f, xproj_w_f, dt_w_f,
        dt_b_f, A_log_f, D_f, sdt, nullptr, clb, xclast, y, NCHR, LCr);
    chunk_k<2><<<g, blk, 0, stream>>>(
        x, proj_w, proj_b, in_w_f, conv_w_f, conv_b_f, xproj_w_f, dt_w_f,
        dt_b_f, A_log_f, D_f, sdt, nullptr, clb, xclast, y, NCHR, LCr);
  }
  tail_k<<<dim3(NB), dim3(512), 0, stream>>>(
      x, proj_w, proj_b, y, in_w_f, out_w_f, in_w_b, conv_w_b, conv_b_b,
      xproj_w_b, dt_w_b, dt_b_b, D_b, out_w_b, fusion_w, fusion_b, ln_g, ln_b,
      (float*)d_out);
}

// Round 7
// 4617.294 us; speedup vs baseline: 1.9400x; 1.0701x over previous
//
#include <hip/hip_runtime.h>
#include <math.h>

#define DM   512     // d_model (== INPUT)
#define DI   1024    // d_inner
#define NS   16      // d_state
#define DTR  32      // dt_rank
#define LSEQ 4096
#define NB   8
#define T    8       // sub-tile timesteps
#define THR  512     // threads per chunk block

__device__ __forceinline__ float siluf(float x) { return x / (1.f + __expf(-x)); }
__device__ __forceinline__ float softplusf(float x) {
  return (x > 20.f) ? x : log1pf(__expf(x));
}

// ---------------------------------------------------------------------------
// Weight fold: W2[m,n] = sum_k in_w[m,k] * proj_w[k,n]   (fp32, M=DI,N=DM,K=DM)
// 64x64 tile, 256 threads.
// ---------------------------------------------------------------------------
__global__ __launch_bounds__(256) void foldW2_k(
    const float* __restrict__ A, const float* __restrict__ B,
    float* __restrict__ C) {
  __shared__ __align__(16) float As[16][68];
  __shared__ __align__(16) float Bs[16][68];
  const int bm = blockIdx.y * 64, bn = blockIdx.x * 64;
  const int tid = threadIdx.x;
  const int tx = tid & 15, ty = tid >> 4;
  const int lr = tid >> 2, lc = (tid & 3) * 4;   // A: row lr, k lc..+3
  const int kk = tid >> 4, nn = (tid & 15) * 4;  // B: k kk, col nn..+3
  float acc[4][4] = {};
  for (int k0 = 0; k0 < DM; k0 += 16) {
    const float4 av = *reinterpret_cast<const float4*>(
        A + (size_t)(bm + lr) * DM + k0 + lc);
    const float4 bv = *reinterpret_cast<const float4*>(
        B + (size_t)(k0 + kk) * DM + bn + nn);
    __syncthreads();
    As[lc + 0][lr] = av.x; As[lc + 1][lr] = av.y;
    As[lc + 2][lr] = av.z; As[lc + 3][lr] = av.w;
    Bs[kk][nn + 0] = bv.x; Bs[kk][nn + 1] = bv.y;
    Bs[kk][nn + 2] = bv.z; Bs[kk][nn + 3] = bv.w;
    __syncthreads();
#pragma unroll
    for (int k = 0; k < 16; ++k) {
      const float4 a4 = *reinterpret_cast<const float4*>(&As[k][ty * 4]);
      const float4 b4 = *reinterpret_cast<const float4*>(&Bs[k][tx * 4]);
      float a[4] = {a4.x, a4.y, a4.z, a4.w};
      float b[4] = {b4.x, b4.y, b4.z, b4.w};
#pragma unroll
      for (int i = 0; i < 4; ++i)
#pragma unroll
        for (int j = 0; j < 4; ++j) acc[i][j] = fmaf(a[i], b[j], acc[i][j]);
    }
  }
#pragma unroll
  for (int i = 0; i < 4; ++i) {
    *reinterpret_cast<float4*>(C + (size_t)(bm + ty * 4 + i) * DM + bn + tx * 4) =
        make_float4(acc[i][0], acc[i][1], acc[i][2], acc[i][3]);
  }
}

// b2[d] = sum_j in_w[d,j] * proj_b[j]
__global__ __launch_bounds__(256) void foldb2_k(
    const float* __restrict__ in_w, const float* __restrict__ pb,
    float* __restrict__ b2) {
  __shared__ float pbs[DM];
  const int t = threadIdx.x;
  for (int i = t; i < DM; i += 256) pbs[i] = pb[i];
  __syncthreads();
  const int d = blockIdx.x * 256 + t;
  const float* wr = in_w + (size_t)d * DM;
  float s = 0.f;
  for (int k = 0; k < DM; k += 4) {
    const float4 wv = *reinterpret_cast<const float4*>(wr + k);
    s = fmaf(pbs[k], wv.x, s);     s = fmaf(pbs[k + 1], wv.y, s);
    s = fmaf(pbs[k + 2], wv.z, s); s = fmaf(pbs[k + 3], wv.w, s);
  }
  b2[d] = s;
}

// ---------------------------------------------------------------------------
// Fused chunk kernel. Block = (chunk c, batch b), 512 threads, 2 ch/thread.
// xa = x @ W2^T + b2 (xp folded away) -> conv/silu -> xdb -> dt -> scan
// partials. Stores sdt + S to ws; fold_k combines.
// ---------------------------------------------------------------------------
__global__ __launch_bounds__(THR, 4) void chunk_k(
    const float* __restrict__ x, const float* __restrict__ W2,
    const float* __restrict__ b2, const float* __restrict__ conv_w,
    const float* __restrict__ conv_b, const float* __restrict__ xproj_w,
    const float* __restrict__ dt_w, const float* __restrict__ dt_b,
    const float* __restrict__ A_log, float* __restrict__ sdtbuf,
    float* __restrict__ Sbuf, float* __restrict__ clb,
    float* __restrict__ xclast, int NCHR, int LCr) {
  __shared__ __align__(16) float xs[T][DM];    // 16 KB
  __shared__ __align__(16) float xcs[T][DI];   // 32 KB
  __shared__ __align__(16) float xdbs[T][72];  // 2.25 KB

  const int tid = threadIdx.x;
  const int c = blockIdx.x, b = blockIdx.y;
  const int t0 = c * LCr;
  const int d0 = tid * 2;   // this thread owns channels d0, d0+1

  float cw[2][4], cb2[2], dtb2[2], bb2[2];
#pragma unroll
  for (int di = 0; di < 2; ++di) {
    const int d = d0 + di;
#pragma unroll
    for (int k = 0; k < 4; ++k) cw[di][k] = conv_w[d * 4 + k];
    cb2[di] = conv_b[d];
    dtb2[di] = dt_b[d];
    bb2[di] = b2[d];
  }

  float Ac[2][NS], S[2][NS];
  float sdt2[2] = {0.f, 0.f};
#pragma unroll
  for (int di = 0; di < 2; ++di)
#pragma unroll
    for (int n = 0; n < NS; ++n) {
      Ac[di][n] = -__expf(A_log[(d0 + di) * NS + n]);
      S[di][n] = 0.f;
    }

  auto fill_xs = [&](int grow, int rows) {
    const int tot = rows * (DM / 4);
    for (int i = tid; i < tot; i += THR) {
      const int r = i >> 7, kk = (i & 127) * 4;
      *reinterpret_cast<float4*>(&xs[r][kk]) =
          *reinterpret_cast<const float4*>(x + ((size_t)grow + r) * DM + kk);
    }
  };

  // xa for 2 channels over `rows` timesteps: a[di][t] = b2 + xs[t,:].W2[d,:]
  auto xa2 = [&](int rows, float (*a)[T]) {
    for (int t = 0; t < rows; ++t) { a[0][t] = bb2[0]; a[1][t] = bb2[1]; }
    const float* w0p = W2 + (size_t)d0 * DM;
    const float* w1p = w0p + DM;
    for (int k0 = 0; k0 < DM; k0 += 4) {
      const float4 wa = *reinterpret_cast<const float4*>(w0p + k0);
      const float4 wb = *reinterpret_cast<const float4*>(w1p + k0);
      for (int t = 0; t < rows; ++t) {
        const float4 xv = *reinterpret_cast<const float4*>(&xs[t][k0]);
        a[0][t] = fmaf(xv.x, wa.x, a[0][t]); a[0][t] = fmaf(xv.y, wa.y, a[0][t]);
        a[0][t] = fmaf(xv.z, wa.z, a[0][t]); a[0][t] = fmaf(xv.w, wa.w, a[0][t]);
        a[1][t] = fmaf(xv.x, wb.x, a[1][t]); a[1][t] = fmaf(xv.y, wb.y, a[1][t]);
        a[1][t] = fmaf(xv.z, wb.z, a[1][t]); a[1][t] = fmaf(xv.w, wb.w, a[1][t]);
      }
    }
  };

  // ---- pre-stage: conv carries (pre-conv xa at t0-3..t0-1) ----
  float cx[2][3];
#pragma unroll
  for (int di = 0; di < 2; ++di) cx[di][0] = cx[di][1] = cx[di][2] = 0.f;
  if (c > 0) {
    fill_xs(b * LSEQ + t0 - 3, 3);
    __syncthreads();
    float a[2][T];
    xa2(3, a);
#pragma unroll
    for (int di = 0; di < 2; ++di) {
      cx[di][0] = a[di][0]; cx[di][1] = a[di][1]; cx[di][2] = a[di][2];
    }
  }

  // ---- main loop over sub-tiles ----
  for (int tt = 0; tt < LCr; tt += T) {
    const int grow = b * LSEQ + t0 + tt;
    __syncthreads();
    fill_xs(grow, T);
    __syncthreads();
    {
      float a[2][T];
      xa2(T, a);
#pragma unroll
      for (int di = 0; di < 2; ++di) {
#pragma unroll
        for (int t = 0; t < T; ++t) {
          const float o = cb2[di] + cw[di][0] * cx[di][0] +
                          cw[di][1] * cx[di][1] + cw[di][2] * cx[di][2] +
                          cw[di][3] * a[di][t];
          cx[di][0] = cx[di][1]; cx[di][1] = cx[di][2]; cx[di][2] = a[di][t];
          xcs[t][d0 + di] = siluf(o);
        }
      }
    }
    __syncthreads();
    // xdb = xc @ xproj_w.T : one output per thread (t = tid>>6, n = tid&63)
    {
      const int t = tid >> 6;
      const int n0 = tid & 63;
      const float* wp = xproj_w + (size_t)n0 * DI;
      float s = 0.f;
      for (int k0 = 0; k0 < DI; k0 += 8) {
        const float4 w0 = *reinterpret_cast<const float4*>(wp + k0);
        const float4 w1 = *reinterpret_cast<const float4*>(wp + k0 + 4);
        const float4 v0 = *reinterpret_cast<const float4*>(&xcs[t][k0]);
        const float4 v1 = *reinterpret_cast<const float4*>(&xcs[t][k0 + 4]);
        s = fmaf(v0.x, w0.x, s); s = fmaf(v0.y, w0.y, s);
        s = fmaf(v0.z, w0.z, s); s = fmaf(v0.w, w0.w, s);
        s = fmaf(v1.x, w1.x, s); s = fmaf(v1.y, w1.y, s);
        s = fmaf(v1.z, w1.z, s); s = fmaf(v1.w, w1.w, s);
      }
      xdbs[t][n0] = s;
    }
    __syncthreads();
    // dt + scan partial update (2 channels per thread)
    {
      float raw0[T], raw1[T];
#pragma unroll
      for (int t = 0; t < T; ++t) { raw0[t] = dtb2[0]; raw1[t] = dtb2[1]; }
      const float* dw0 = dt_w + (size_t)d0 * DTR;
      const float* dw1 = dw0 + DTR;
#pragma unroll
      for (int r0 = 0; r0 < DTR; r0 += 8) {
        const float4 u0 = *reinterpret_cast<const float4*>(dw0 + r0);
        const float4 u1 = *reinterpret_cast<const float4*>(dw0 + r0 + 4);
        const float4 v0 = *reinterpret_cast<const float4*>(dw1 + r0);
        const float4 v1 = *reinterpret_cast<const float4*>(dw1 + r0 + 4);
#pragma unroll
        for (int t = 0; t < T; ++t) {
          const float4 b0 = *reinterpret_cast<const float4*>(&xdbs[t][r0]);
          const float4 b1 = *reinterpret_cast<const float4*>(&xdbs[t][r0 + 4]);
          raw0[t] = fmaf(b0.x, u0.x, raw0[t]); raw0[t] = fmaf(b0.y, u0.y, raw0[t]);
          raw0[t] = fmaf(b0.z, u0.z, raw0[t]); raw0[t] = fmaf(b0.w, u0.w, raw0[t]);
          raw0[t] = fmaf(b1.x, u1.x, raw0[t]); raw0[t] = fmaf(b1.y, u1.y, raw0[t]);
          raw0[t] = fmaf(b1.z, u1.z, raw0[t]); raw0[t] = fmaf(b1.w, u1.w, raw0[t]);
          raw1[t] = fmaf(b0.x, v0.x, raw1[t]); raw1[t] = fmaf(b0.y, v0.y, raw1[t]);
          raw1[t] = fmaf(b0.z, v0.z, raw1[t]); raw1[t] = fmaf(b0.w, v0.w, raw1[t]);
          raw1[t] = fmaf(b1.x, v1.x, raw1[t]); raw1[t] = fmaf(b1.y, v1.y, raw1[t]);
          raw1[t] = fmaf(b1.z, v1.z, raw1[t]); raw1[t] = fmaf(b1.w, v1.w, raw1[t]);
        }
      }
#pragma unroll
      for (int t = 0; t < T; ++t) {
        const float dtv0 = softplusf(raw0[t]);
        const float dtv1 = softplusf(raw1[t]);
        sdt2[0] += dtv0;
        sdt2[1] += dtv1;
        const float w0 = dtv0 * xcs[t][d0];
        const float w1 = dtv1 * xcs[t][d0 + 1];
#pragma unroll
        for (int n = 0; n < NS; ++n) {
          const float Bn = xdbs[t][DTR + n];
          S[0][n] = fmaf(S[0][n], __expf(dtv0 * Ac[0][n]), w0 * Bn);
          S[1][n] = fmaf(S[1][n], __expf(dtv1 * Ac[1][n]), w1 * Bn);
        }
      }
    }
  }

  // ---- epilogue: store chunk partials ----
  const size_t sidx = ((size_t)b * NCHR + c) * DI + d0;
  sdtbuf[sidx] = sdt2[0];
  sdtbuf[sidx + 1] = sdt2[1];
#pragma unroll
  for (int n = 0; n < NS; ++n) {
    float2 v; v.x = S[0][n]; v.y = S[1][n];
    *reinterpret_cast<float2*>(
        Sbuf + (((size_t)b * NCHR + c) * NS + n) * DI + d0) = v;
  }
  if (c == NCHR - 1) {
    xclast[(size_t)b * DI + d0] = xcs[T - 1][d0];
    xclast[(size_t)b * DI + d0 + 1] = xcs[T - 1][d0 + 1];
    if (tid < NS) clb[b * NS + tid] = xdbs[T - 1][DTR + NS + tid];
  }
}

// ---------------------------------------------------------------------------
// Fold chunk partials: h = fold over chunks, y = h.C_last + xc_last*D
// ---------------------------------------------------------------------------
__global__ __launch_bounds__(256) void fold_k(
    const float* __restrict__ sdt, const float* __restrict__ Sb,
    const float* __restrict__ A_log, const float* __restrict__ clb,
    const float* __restrict__ xclast, const float* __restrict__ Dw,
    float* __restrict__ y, int NCHR) {
  const int tid = blockIdx.x * 256 + threadIdx.x;
  const int b = tid >> 10, d = tid & (DI - 1);
  float Ac[NS], h[NS];
#pragma unroll
  for (int n = 0; n < NS; ++n) {
    Ac[n] = -__expf(A_log[d * NS + n]);
    h[n] = 0.f;
  }
  for (int c = 0; c < NCHR; ++c) {
    const float s = sdt[((size_t)b * NCHR + c) * DI + d];
#pragma unroll
    for (int n = 0; n < NS; ++n)
      h[n] = fmaf(h[n], __expf(Ac[n] * s),
                  Sb[(((size_t)b * NCHR + c) * NS + n) * DI + d]);
  }
  float acc = 0.f;
#pragma unroll
  for (int n = 0; n < NS; ++n) acc += h[n] * clb[b * NS + n];
  y[(size_t)b * DI + d] = acc + xclast[(size_t)b * DI + d] * Dw[d];
}

// ---------------------------------------------------------------------------
__device__ __forceinline__ float dotf(const float* lds, const float* w, int n) {
  float s = 0.f;
#pragma unroll 4
  for (int k = 0; k < n; k += 4) {
    const float4 wv = *reinterpret_cast<const float4*>(w + k);
    s = fmaf(lds[k], wv.x, s);
    s = fmaf(lds[k + 1], wv.y, s);
    s = fmaf(lds[k + 2], wv.z, s);
    s = fmaf(lds[k + 3], wv.w, s);
  }
  return s;
}

// Tail: all last-token-only work (fwd gate, entire bwd branch, out/fusion/LN).
__global__ __launch_bounds__(512) void tail_k(
    const float* __restrict__ x, const float* __restrict__ proj_w,
    const float* __restrict__ proj_b, const float* __restrict__ ybuf,
    const float* in_w_f, const float* out_w_f, const float* in_w_b,
    const float* conv_w_b, const float* conv_b_b, const float* xproj_w_b,
    const float* dt_w_b, const float* dt_b_b, const float* D_b,
    const float* out_w_b, const float* fusion_w, const float* fusion_b,
    const float* ln_g, const float* ln_b, float* __restrict__ out) {
  __shared__ float xls[DM];
  __shared__ float xpL[DM];
  __shared__ float xcb[DI];
  __shared__ float zb[DI];
  __shared__ float zf[DI];
  __shared__ float gf[DI];
  __shared__ float gb[DI];
  __shared__ float cat[DI];
  __shared__ float xdbb[64];
  __shared__ float red[DM];
  __shared__ float mu_s, var_s;
  const int b = blockIdx.x, t = threadIdx.x;

  xls[t] = x[((size_t)b * LSEQ + (LSEQ - 1)) * DM + t];
  __syncthreads();
  xpL[t] = proj_b[t] + dotf(xls, proj_w + (size_t)t * DM, DM);
  __syncthreads();

  for (int q = 0; q < 4; ++q) {
    int i = q * 512 + t;
    float s = dotf(xpL, in_w_b + (size_t)i * DM, DM);
    if (i < DI) {
      xcb[i] = siluf(s * conv_w_b[i * 4 + 3] + conv_b_b[i]);
    } else {
      zb[i - DI] = s;
    }
  }
  for (int q = 0; q < 2; ++q) {
    int d = q * 512 + t;
    zf[d] = dotf(xpL, in_w_f + (size_t)(DI + d) * DM, DM);
  }
  __syncthreads();

  if (t < 64) xdbb[t] = dotf(xcb, xproj_w_b + (size_t)t * DI, DI);
  __syncthreads();

  float bc = 0.f;
#pragma unroll
  for (int n = 0; n < NS; ++n) bc += xdbb[DTR + n] * xdbb[DTR + NS + n];

  for (int q = 0; q < 2; ++q) {
    int d = q * 512 + t;
    float raw = dt_b_b[d];
    const float* wr = dt_w_b + (size_t)d * DTR;
#pragma unroll
    for (int r = 0; r < DTR; ++r) raw = fmaf(xdbb[r], wr[r], raw);
    float dtv = softplusf(raw);
    float yb = dtv * xcb[d] * bc + xcb[d] * D_b[d];
    gb[d] = yb * siluf(zb[d]);
    gf[d] = ybuf[(size_t)b * DI + d] * siluf(zf[d]);
  }
  __syncthreads();

  cat[t] = dotf(gf, out_w_f + (size_t)t * DI, DI);
  cat[DM + t] = dotf(gb, out_w_b + (size_t)t * DI, DI);
  __syncthreads();

  float rv = fusion_b[t] + dotf(cat, fusion_w + (size_t)t * DI, DI);

  red[t] = rv;
  __syncthreads();
  for (int s = 256; s > 0; s >>= 1) {
    if (t < s) red[t] += red[t + s];
    __syncthreads();
  }
  if (t == 0) mu_s = red[0] * (1.f / DM);
  __syncthreads();
  float dv = rv - mu_s;
  red[t] = dv * dv;
  __syncthreads();
  for (int s = 256; s > 0; s >>= 1) {
    if (t < s) red[t] += red[t + s];
    __syncthreads();
  }
  if (t == 0) var_s = red[0] * (1.f / DM);
  __syncthreads();
  out[(size_t)b * DM + t] = dv * rsqrtf(var_s + 1e-5f) * ln_g[t] + ln_b[t];
}

// ---------------------------------------------------------------------------
static size_t plan_need(int nch, size_t* offs) {
  size_t o = 0;
  int idx = 0;
  auto al = [&](size_t n) {
    size_t q = (o + 255) & ~(size_t)255;
    o = q + n;
    if (offs) offs[idx] = q;
    ++idx;
  };
  al((size_t)DI * DM * 4);               // 0: W2
  al((size_t)DI * 4);                    // 1: b2
  al((size_t)NB * DI * 4);               // 2: y
  al((size_t)NB * nch * DI * 4);         // 3: sdt
  al((size_t)NB * NS * 4);               // 4: clb
  al((size_t)NB * DI * 4);               // 5: xclast
  al((size_t)NB * nch * NS * DI * 4);    // 6: Sb
  return o;
}

extern "C" void kernel_launch(void* const* d_in, const int* in_sizes, int n_in,
                              void* d_out, int out_size, void* d_ws,
                              size_t ws_size, hipStream_t stream) {
  (void)in_sizes; (void)n_in; (void)out_size;
  const float* x        = (const float*)d_in[0];
  const float* proj_w   = (const float*)d_in[1];
  const float* proj_b   = (const float*)d_in[2];
  const float* in_w_f   = (const float*)d_in[3];
  const float* conv_w_f = (const float*)d_in[4];
  const float* conv_b_f = (const float*)d_in[5];
  const float* xproj_w_f= (const float*)d_in[6];
  const float* dt_w_f   = (const float*)d_in[7];
  const float* dt_b_f   = (const float*)d_in[8];
  const float* A_log_f  = (const float*)d_in[9];
  const float* D_f      = (const float*)d_in[10];
  const float* out_w_f  = (const float*)d_in[11];
  const float* in_w_b   = (const float*)d_in[12];
  const float* conv_w_b = (const float*)d_in[13];
  const float* conv_b_b = (const float*)d_in[14];
  const float* xproj_w_b= (const float*)d_in[15];
  const float* dt_w_b   = (const float*)d_in[16];
  const float* dt_b_b   = (const float*)d_in[17];
  // d_in[18] = A_log_b unused (bwd branch only needs t=0, where h0 = 0)
  const float* D_b      = (const float*)d_in[19];
  const float* out_w_b  = (const float*)d_in[20];
  const float* fusion_w = (const float*)d_in[21];
  const float* fusion_b = (const float*)d_in[22];
  const float* ln_g     = (const float*)d_in[23];
  const float* ln_b     = (const float*)d_in[24];

  // Ladder (host-constant wrt ws_size -> graph-safe). R6 proved ws >= 35.7MB,
  // so the 32-tier (20.9MB) always fits.
  int NCHR;
  if (ws_size >= plan_need(128, nullptr)) NCHR = 128;       // 73.6 MB
  else if (ws_size >= plan_need(64, nullptr)) NCHR = 64;    // 37.9 MB
  else NCHR = 32;                                           // 20.9 MB
  const int LCr = LSEQ / NCHR;

  size_t offs[7];
  plan_need(NCHR, offs);
  char* base = (char*)d_ws;
  float* W2     = (float*)(base + offs[0]);
  float* b2     = (float*)(base + offs[1]);
  float* y      = (float*)(base + offs[2]);
  float* sdt    = (float*)(base + offs[3]);
  float* clb    = (float*)(base + offs[4]);
  float* xclast = (float*)(base + offs[5]);
  float* Sb     = (float*)(base + offs[6]);

  foldb2_k<<<dim3(DI / 256), dim3(256), 0, stream>>>(in_w_f, proj_b, b2);
  foldW2_k<<<dim3(DM / 64, DI / 64), dim3(256), 0, stream>>>(in_w_f, proj_w, W2);
  chunk_k<<<dim3(NCHR, NB), dim3(THR), 0, stream>>>(
      x, W2, b2, conv_w_f, conv_b_f, xproj_w_f, dt_w_f, dt_b_f, A_log_f,
      sdt, Sb, clb, xclast, NCHR, LCr);
  fold_k<<<dim3((NB * DI) / 256), dim3(256), 0, stream>>>(
      sdt, Sb, A_log_f, clb, xclast, D_f, y, NCHR);
  tail_k<<<dim3(NB), dim3(512), 0, stream>>>(
      x, proj_w, proj_b, y, in_w_f, out_w_f, in_w_b, conv_w_b, conv_b_b,
      xproj_w_b, dt_w_b, dt_b_b, D_b, out_w_b, fusion_w, fusion_b, ln_g, ln_b,
      (float*)d_out);
}

// Round 9
// 4509.903 us; speedup vs baseline: 1.9862x; 1.0238x over previous
//
#include <hip/hip_runtime.h>
#include <math.h>

#define DM   512     // d_model (== INPUT)
#define DI   1024    // d_inner
#define NS   16      // d_state
#define DTR  32      // dt_rank
#define LSEQ 4096
#define NB   8
#define T    8       // sub-tile timesteps
#define THR  512     // threads per chunk block

typedef float f32x2 __attribute__((ext_vector_type(2)));

__device__ __forceinline__ float siluf(float x) { return x / (1.f + __expf(-x)); }
__device__ __forceinline__ float softplusf(float x) {
  return (x > 20.f) ? x : log1pf(__expf(x));
}

// ---------------------------------------------------------------------------
// W2T[i][d] = sum_j in_w[d][j] * proj_w[j][i]   (stored TRANSPOSED: [DM][DI])
// 64x64 tile GEMM, transposed store.
// ---------------------------------------------------------------------------
__global__ __launch_bounds__(256) void foldW2T_k(
    const float* __restrict__ A,   // in_w_f[:DI]  (DI x DM)
    const float* __restrict__ B,   // proj_w       (DM x DM)
    float* __restrict__ CT) {      // W2T          (DM x DI)
  __shared__ __align__(16) float As[16][68];
  __shared__ __align__(16) float Bs[16][68];
  const int bm = blockIdx.y * 64, bn = blockIdx.x * 64;
  const int tid = threadIdx.x;
  const int tx = tid & 15, ty = tid >> 4;
  const int lr = tid >> 2, lc = (tid & 3) * 4;
  const int kk = tid >> 4, nn = (tid & 15) * 4;
  float acc[4][4] = {};
  for (int k0 = 0; k0 < DM; k0 += 16) {
    const float4 av = *reinterpret_cast<const float4*>(
        A + (size_t)(bm + lr) * DM + k0 + lc);
    const float4 bv = *reinterpret_cast<const float4*>(
        B + (size_t)(k0 + kk) * DM + bn + nn);
    __syncthreads();
    As[lc + 0][lr] = av.x; As[lc + 1][lr] = av.y;
    As[lc + 2][lr] = av.z; As[lc + 3][lr] = av.w;
    Bs[kk][nn + 0] = bv.x; Bs[kk][nn + 1] = bv.y;
    Bs[kk][nn + 2] = bv.z; Bs[kk][nn + 3] = bv.w;
    __syncthreads();
#pragma unroll
    for (int k = 0; k < 16; ++k) {
      const float4 a4 = *reinterpret_cast<const float4*>(&As[k][ty * 4]);
      const float4 b4 = *reinterpret_cast<const float4*>(&Bs[k][tx * 4]);
      float a[4] = {a4.x, a4.y, a4.z, a4.w};
      float b[4] = {b4.x, b4.y, b4.z, b4.w};
#pragma unroll
      for (int i = 0; i < 4; ++i)
#pragma unroll
        for (int j = 0; j < 4; ++j) acc[i][j] = fmaf(a[i], b[j], acc[i][j]);
    }
  }
  // transposed store: CT[i_col][d_row]
#pragma unroll
  for (int i = 0; i < 4; ++i)
#pragma unroll
    for (int j = 0; j < 4; ++j)
      CT[(size_t)(bn + tx * 4 + j) * DI + (bm + ty * 4 + i)] = acc[i][j];
}

// b2[d] = sum_j in_w[d,j] * proj_b[j]
__global__ __launch_bounds__(256) void foldb2_k(
    const float* __restrict__ in_w, const float* __restrict__ pb,
    float* __restrict__ b2) {
  __shared__ float pbs[DM];
  const int t = threadIdx.x;
  for (int i = t; i < DM; i += 256) pbs[i] = pb[i];
  __syncthreads();
  const int d = blockIdx.x * 256 + t;
  const float* wr = in_w + (size_t)d * DM;
  float s = 0.f;
  for (int k = 0; k < DM; k += 4) {
    const float4 wv = *reinterpret_cast<const float4*>(wr + k);
    s = fmaf(pbs[k], wv.x, s);     s = fmaf(pbs[k + 1], wv.y, s);
    s = fmaf(pbs[k + 2], wv.z, s); s = fmaf(pbs[k + 3], wv.w, s);
  }
  b2[d] = s;
}

// xprojB[kb*64+n] = float4{ xproj_w[n][4kb+j] }  (kb<DI/4, n<64)
__global__ __launch_bounds__(256) void xprojB_k(
    const float* __restrict__ xproj_w, float4* __restrict__ out) {
  const int id = blockIdx.x * 256 + threadIdx.x;  // < (DI/4)*64
  const int kb = id >> 6, n = id & 63;
  float4 v;
  v.x = xproj_w[(size_t)n * DI + 4 * kb + 0];
  v.y = xproj_w[(size_t)n * DI + 4 * kb + 1];
  v.z = xproj_w[(size_t)n * DI + 4 * kb + 2];
  v.w = xproj_w[(size_t)n * DI + 4 * kb + 3];
  out[id] = v;
}

// dtwT[r][d] = dt_w[d][r]
__global__ __launch_bounds__(256) void dtwT_k(
    const float* __restrict__ dt_w, float* __restrict__ out) {
  const int id = blockIdx.x * 256 + threadIdx.x;  // < DTR*DI
  const int r = id >> 10, d = id & (DI - 1);
  out[id] = dt_w[(size_t)d * DTR + r];
}

// ---------------------------------------------------------------------------
// Fused chunk kernel. Block = (chunk c, batch b), 512 threads, 2 ch/thread.
// All weight loads coalesced via transposed layouts.
// ---------------------------------------------------------------------------
__global__ __launch_bounds__(THR, 4) void chunk_k(
    const float* __restrict__ x, const float* __restrict__ W2T,
    const float* __restrict__ b2, const float* __restrict__ conv_w,
    const float* __restrict__ conv_b, const float4* __restrict__ xprojB,
    const float* __restrict__ dtwT, const float* __restrict__ dt_b,
    const float* __restrict__ A_log, float* __restrict__ sdtbuf,
    float* __restrict__ Sbuf, float* __restrict__ clb,
    float* __restrict__ xclast, int NCHR, int LCr) {
  __shared__ __align__(16) float xs[T][DM];    // 16 KB
  __shared__ __align__(16) float xcs[T][DI];   // 32 KB
  __shared__ __align__(16) float xdbs[T][72];  // 2.25 KB

  const int tid = threadIdx.x;
  const int c = blockIdx.x, b = blockIdx.y;
  const int t0 = c * LCr;
  const int d0 = tid * 2;   // this thread owns channels d0, d0+1

  float cw[2][4], cb2[2], dtb2[2], bb2[2];
#pragma unroll
  for (int di = 0; di < 2; ++di) {
    const int d = d0 + di;
#pragma unroll
    for (int k = 0; k < 4; ++k) cw[di][k] = conv_w[d * 4 + k];
    cb2[di] = conv_b[d];
    dtb2[di] = dt_b[d];
    bb2[di] = b2[d];
  }

  float Ac[2][NS], S[2][NS];
  float sdt2[2] = {0.f, 0.f};
#pragma unroll
  for (int di = 0; di < 2; ++di)
#pragma unroll
    for (int n = 0; n < NS; ++n) {
      Ac[di][n] = -__expf(A_log[(d0 + di) * NS + n]);
      S[di][n] = 0.f;
    }

  auto fill_xs = [&](int grow, int rows) {
    const int tot = rows * (DM / 4);
    for (int i = tid; i < tot; i += THR) {
      const int r = i >> 7, kk = (i & 127) * 4;
      *reinterpret_cast<float4*>(&xs[r][kk]) =
          *reinterpret_cast<const float4*>(x + ((size_t)grow + r) * DM + kk);
    }
  };

  // xa for 2 channels over all T timesteps (coalesced W2T float2 loads).
  auto xa2 = [&](float (*a)[T]) {
#pragma unroll
    for (int t = 0; t < T; ++t) { a[0][t] = bb2[0]; a[1][t] = bb2[1]; }
    for (int k0 = 0; k0 < DM; k0 += 4) {
      const float2 w0 = *reinterpret_cast<const float2*>(W2T + (size_t)(k0 + 0) * DI + d0);
      const float2 w1 = *reinterpret_cast<const float2*>(W2T + (size_t)(k0 + 1) * DI + d0);
      const float2 w2 = *reinterpret_cast<const float2*>(W2T + (size_t)(k0 + 2) * DI + d0);
      const float2 w3 = *reinterpret_cast<const float2*>(W2T + (size_t)(k0 + 3) * DI + d0);
#pragma unroll
      for (int t = 0; t < T; ++t) {
        const float4 xv = *reinterpret_cast<const float4*>(&xs[t][k0]);
        a[0][t] = fmaf(xv.x, w0.x, a[0][t]); a[1][t] = fmaf(xv.x, w0.y, a[1][t]);
        a[0][t] = fmaf(xv.y, w1.x, a[0][t]); a[1][t] = fmaf(xv.y, w1.y, a[1][t]);
        a[0][t] = fmaf(xv.z, w2.x, a[0][t]); a[1][t] = fmaf(xv.z, w2.y, a[1][t]);
        a[0][t] = fmaf(xv.w, w3.x, a[0][t]); a[1][t] = fmaf(xv.w, w3.y, a[1][t]);
      }
    }
  };

  // ---- pre-stage: conv carries (pre-conv xa at t0-3..t0-1) ----
  float cx[2][3];
#pragma unroll
  for (int di = 0; di < 2; ++di) cx[di][0] = cx[di][1] = cx[di][2] = 0.f;
  if (c > 0) {
    fill_xs(b * LSEQ + t0 - 3, 3);
    __syncthreads();
    float a[2][T];
    xa2(a);  // rows 3..7 are garbage, discarded
#pragma unroll
    for (int di = 0; di < 2; ++di) {
      cx[di][0] = a[di][0]; cx[di][1] = a[di][1]; cx[di][2] = a[di][2];
    }
  }

  // ---- main loop over sub-tiles ----
  for (int tt = 0; tt < LCr; tt += T) {
    const int grow = b * LSEQ + t0 + tt;
    __syncthreads();
    fill_xs(grow, T);
    __syncthreads();
    {
      float a[2][T];
      xa2(a);
#pragma unroll
      for (int di = 0; di < 2; ++di) {
#pragma unroll
        for (int t = 0; t < T; ++t) {
          const float o = cb2[di] + cw[di][0] * cx[di][0] +
                          cw[di][1] * cx[di][1] + cw[di][2] * cx[di][2] +
                          cw[di][3] * a[di][t];
          cx[di][0] = cx[di][1]; cx[di][1] = cx[di][2]; cx[di][2] = a[di][t];
          xcs[t][d0 + di] = siluf(o);
        }
      }
    }
    __syncthreads();
    // xdb: thread (t = tid>>6, n = tid&63); xprojB loads coalesced 16B/lane
    {
      const int t = tid >> 6;
      const int n0 = tid & 63;
      float s = 0.f;
      for (int kb = 0; kb < DI / 4; ++kb) {
        const float4 wv = xprojB[kb * 64 + n0];
        const float4 xv = *reinterpret_cast<const float4*>(&xcs[t][kb * 4]);
        s = fmaf(xv.x, wv.x, s); s = fmaf(xv.y, wv.y, s);
        s = fmaf(xv.z, wv.z, s); s = fmaf(xv.w, wv.w, s);
      }
      xdbs[t][n0] = s;
    }
    __syncthreads();
    // dt + scan partial update (2 channels per thread), dtwT coalesced
    {
      float raw0[T], raw1[T];
#pragma unroll
      for (int t = 0; t < T; ++t) { raw0[t] = dtb2[0]; raw1[t] = dtb2[1]; }
      for (int r0 = 0; r0 < DTR; r0 += 4) {
        const float2 u0 = *reinterpret_cast<const float2*>(dtwT + (size_t)(r0 + 0) * DI + d0);
        const float2 u1 = *reinterpret_cast<const float2*>(dtwT + (size_t)(r0 + 1) * DI + d0);
        const float2 u2 = *reinterpret_cast<const float2*>(dtwT + (size_t)(r0 + 2) * DI + d0);
        const float2 u3 = *reinterpret_cast<const float2*>(dtwT + (size_t)(r0 + 3) * DI + d0);
#pragma unroll
        for (int t = 0; t < T; ++t) {
          const float4 bv = *reinterpret_cast<const float4*>(&xdbs[t][r0]);
          raw0[t] = fmaf(bv.x, u0.x, raw0[t]); raw1[t] = fmaf(bv.x, u0.y, raw1[t]);
          raw0[t] = fmaf(bv.y, u1.x, raw0[t]); raw1[t] = fmaf(bv.y, u1.y, raw1[t]);
          raw0[t] = fmaf(bv.z, u2.x, raw0[t]); raw1[t] = fmaf(bv.z, u2.y, raw1[t]);
          raw0[t] = fmaf(bv.w, u3.x, raw0[t]); raw1[t] = fmaf(bv.w, u3.y, raw1[t]);
        }
      }
#pragma unroll
      for (int t = 0; t < T; ++t) {
        const float dtv0 = softplusf(raw0[t]);
        const float dtv1 = softplusf(raw1[t]);
        sdt2[0] += dtv0;
        sdt2[1] += dtv1;
        const float w0 = dtv0 * xcs[t][d0];
        const float w1 = dtv1 * xcs[t][d0 + 1];
#pragma unroll
        for (int n = 0; n < NS; ++n) {
          const float Bn = xdbs[t][DTR + n];
          S[0][n] = fmaf(S[0][n], __expf(dtv0 * Ac[0][n]), w0 * Bn);
          S[1][n] = fmaf(S[1][n], __expf(dtv1 * Ac[1][n]), w1 * Bn);
        }
      }
    }
  }

  // ---- epilogue: store chunk partials (non-temporal: keep L2 for weights) --
  {
    f32x2 sv; sv.x = sdt2[0]; sv.y = sdt2[1];
    __builtin_nontemporal_store(
        sv, reinterpret_cast<f32x2*>(sdtbuf + ((size_t)b * NCHR + c) * DI + d0));
#pragma unroll
    for (int n = 0; n < NS; ++n) {
      f32x2 v; v.x = S[0][n]; v.y = S[1][n];
      __builtin_nontemporal_store(
          v, reinterpret_cast<f32x2*>(
                 Sbuf + (((size_t)b * NCHR + c) * NS + n) * DI + d0));
    }
  }
  if (c == NCHR - 1) {
    xclast[(size_t)b * DI + d0] = xcs[T - 1][d0];
    xclast[(size_t)b * DI + d0 + 1] = xcs[T - 1][d0 + 1];
    if (tid < NS) clb[b * NS + tid] = xdbs[T - 1][DTR + NS + tid];
  }
}

// ---------------------------------------------------------------------------
// Fold chunk partials: h = fold over chunks, y = h.C_last + xc_last*D
// ---------------------------------------------------------------------------
__global__ __launch_bounds__(256) void fold_k(
    const float* __restrict__ sdt, const float* __restrict__ Sb,
    const float* __restrict__ A_log, const float* __restrict__ clb,
    const float* __restrict__ xclast, const float* __restrict__ Dw,
    float* __restrict__ y, int NCHR) {
  const int tid = blockIdx.x * 256 + threadIdx.x;
  const int b = tid >> 10, d = tid & (DI - 1);
  float Ac[NS], h[NS];
#pragma unroll
  for (int n = 0; n < NS; ++n) {
    Ac[n] = -__expf(A_log[d * NS + n]);
    h[n] = 0.f;
  }
  for (int c = 0; c < NCHR; ++c) {
    const float s = sdt[((size_t)b * NCHR + c) * DI + d];
#pragma unroll
    for (int n = 0; n < NS; ++n)
      h[n] = fmaf(h[n], __expf(Ac[n] * s),
                  Sb[(((size_t)b * NCHR + c) * NS + n) * DI + d]);
  }
  float acc = 0.f;
#pragma unroll
  for (int n = 0; n < NS; ++n) acc += h[n] * clb[b * NS + n];
  y[(size_t)b * DI + d] = acc + xclast[(size_t)b * DI + d] * Dw[d];
}

// ---------------------------------------------------------------------------
__device__ __forceinline__ float dotf(const float* lds, const float* w, int n) {
  float s = 0.f;
#pragma unroll 4
  for (int k = 0; k < n; k += 4) {
    const float4 wv = *reinterpret_cast<const float4*>(w + k);
    s = fmaf(lds[k], wv.x, s);
    s = fmaf(lds[k + 1], wv.y, s);
    s = fmaf(lds[k + 2], wv.z, s);
    s = fmaf(lds[k + 3], wv.w, s);
  }
  return s;
}

// Tail: all last-token-only work (fwd gate, entire bwd branch, out/fusion/LN).
__global__ __launch_bounds__(512) void tail_k(
    const float* __restrict__ x, const float* __restrict__ proj_w,
    const float* __restrict__ proj_b, const float* __restrict__ ybuf,
    const float* in_w_f, const float* out_w_f, const float* in_w_b,
    const float* conv_w_b, const float* conv_b_b, const float* xproj_w_b,
    const float* dt_w_b, const float* dt_b_b, const float* D_b,
    const float* out_w_b, const float* fusion_w, const float* fusion_b,
    const float* ln_g, const float* ln_b, float* __restrict__ out) {
  __shared__ float xls[DM];
  __shared__ float xpL[DM];
  __shared__ float xcb[DI];
  __shared__ float zb[DI];
  __shared__ float zf[DI];
  __shared__ float gf[DI];
  __shared__ float gb[DI];
  __shared__ float cat[DI];
  __shared__ float xdbb[64];
  __shared__ float red[DM];
  __shared__ float mu_s, var_s;
  const int b = blockIdx.x, t = threadIdx.x;

  xls[t] = x[((size_t)b * LSEQ + (LSEQ - 1)) * DM + t];
  __syncthreads();
  xpL[t] = proj_b[t] + dotf(xls, proj_w + (size_t)t * DM, DM);
  __syncthreads();

  for (int q = 0; q < 4; ++q) {
    int i = q * 512 + t;
    float s = dotf(xpL, in_w_b + (size_t)i * DM, DM);
    if (i < DI) {
      xcb[i] = siluf(s * conv_w_b[i * 4 + 3] + conv_b_b[i]);
    } else {
      zb[i - DI] = s;
    }
  }
  for (int q = 0; q < 2; ++q) {
    int d = q * 512 + t;
    zf[d] = dotf(xpL, in_w_f + (size_t)(DI + d) * DM, DM);
  }
  __syncthreads();

  if (t < 64) xdbb[t] = dotf(xcb, xproj_w_b + (size_t)t * DI, DI);
  __syncthreads();

  float bc = 0.f;
#pragma unroll
  for (int n = 0; n < NS; ++n) bc += xdbb[DTR + n] * xdbb[DTR + NS + n];

  for (int q = 0; q < 2; ++q) {
    int d = q * 512 + t;
    float raw = dt_b_b[d];
    const float* wr = dt_w_b + (size_t)d * DTR;
#pragma unroll
    for (int r = 0; r < DTR; ++r) raw = fmaf(xdbb[r], wr[r], raw);
    float dtv = softplusf(raw);
    float yb = dtv * xcb[d] * bc + xcb[d] * D_b[d];
    gb[d] = yb * siluf(zb[d]);
    gf[d] = ybuf[(size_t)b * DI + d] * siluf(zf[d]);
  }
  __syncthreads();

  cat[t] = dotf(gf, out_w_f + (size_t)t * DI, DI);
  cat[DM + t] = dotf(gb, out_w_b + (size_t)t * DI, DI);
  __syncthreads();

  float rv = fusion_b[t] + dotf(cat, fusion_w + (size_t)t * DI, DI);

  red[t] = rv;
  __syncthreads();
  for (int s = 256; s > 0; s >>= 1) {
    if (t < s) red[t] += red[t + s];
    __syncthreads();
  }
  if (t == 0) mu_s = red[0] * (1.f / DM);
  __syncthreads();
  float dv = rv - mu_s;
  red[t] = dv * dv;
  __syncthreads();
  for (int s = 256; s > 0; s >>= 1) {
    if (t < s) red[t] += red[t + s];
    __syncthreads();
  }
  if (t == 0) var_s = red[0] * (1.f / DM);
  __syncthreads();
  out[(size_t)b * DM + t] = dv * rsqrtf(var_s + 1e-5f) * ln_g[t] + ln_b[t];
}

// ---------------------------------------------------------------------------
static size_t plan_need(int nch, size_t* offs) {
  size_t o = 0;
  int idx = 0;
  auto al = [&](size_t n) {
    size_t q = (o + 255) & ~(size_t)255;
    o = q + n;
    if (offs) offs[idx] = q;
    ++idx;
  };
  al((size_t)DM * DI * 4);               // 0: W2T
  al((size_t)DI * 4);                    // 1: b2
  al((size_t)(DI / 4) * 64 * 16);        // 2: xprojB
  al((size_t)DTR * DI * 4);              // 3: dtwT
  al((size_t)NB * DI * 4);               // 4: y
  al((size_t)NB * nch * DI * 4);         // 5: sdt
  al((size_t)NB * NS * 4);               // 6: clb
  al((size_t)NB * DI * 4);               // 7: xclast
  al((size_t)NB * nch * NS * DI * 4);    // 8: Sb
  return o;
}

extern "C" void kernel_launch(void* const* d_in, const int* in_sizes, int n_in,
                              void* d_out, int out_size, void* d_ws,
                              size_t ws_size, hipStream_t stream) {
  (void)in_sizes; (void)n_in; (void)out_size;
  const float* x        = (const float*)d_in[0];
  const float* proj_w   = (const float*)d_in[1];
  const float* proj_b   = (const float*)d_in[2];
  const float* in_w_f   = (const float*)d_in[3];
  const float* conv_w_f = (const float*)d_in[4];
  const float* conv_b_f = (const float*)d_in[5];
  const float* xproj_w_f= (const float*)d_in[6];
  const float* dt_w_f   = (const float*)d_in[7];
  const float* dt_b_f   = (const float*)d_in[8];
  const float* A_log_f  = (const float*)d_in[9];
  const float* D_f      = (const float*)d_in[10];
  const float* out_w_f  = (const float*)d_in[11];
  const float* in_w_b   = (const float*)d_in[12];
  const float* conv_w_b = (const float*)d_in[13];
  const float* conv_b_b = (const float*)d_in[14];
  const float* xproj_w_b= (const float*)d_in[15];
  const float* dt_w_b   = (const float*)d_in[16];
  const float* dt_b_b   = (const float*)d_in[17];
  // d_in[18] = A_log_b unused (bwd branch only needs t=0, where h0 = 0)
  const float* D_b      = (const float*)d_in[19];
  const float* out_w_b  = (const float*)d_in[20];
  const float* fusion_w = (const float*)d_in[21];
  const float* fusion_b = (const float*)d_in[22];
  const float* ln_g     = (const float*)d_in[23];
  const float* ln_b     = (const float*)d_in[24];

  // Ladder (host-constant wrt ws_size -> graph-safe). R6 proved ws >= 35.7MB.
  int NCHR;
  if (ws_size >= plan_need(128, nullptr)) NCHR = 128;
  else if (ws_size >= plan_need(64, nullptr)) NCHR = 64;
  else NCHR = 32;
  const int LCr = LSEQ / NCHR;

  size_t offs[9];
  plan_need(NCHR, offs);
  char* base = (char*)d_ws;
  float*  W2T    = (float*)(base + offs[0]);
  float*  b2     = (float*)(base + offs[1]);
  float4* xprojB = (float4*)(base + offs[2]);
  float*  dtwT   = (float*)(base + offs[3]);
  float*  y      = (float*)(base + offs[4]);
  float*  sdt    = (float*)(base + offs[5]);
  float*  clb    = (float*)(base + offs[6]);
  float*  xclast = (float*)(base + offs[7]);
  float*  Sb     = (float*)(base + offs[8]);

  foldb2_k<<<dim3(DI / 256), dim3(256), 0, stream>>>(in_w_f, proj_b, b2);
  foldW2T_k<<<dim3(DM / 64, DI / 64), dim3(256), 0, stream>>>(in_w_f, proj_w, W2T);
  xprojB_k<<<dim3((DI / 4) * 64 / 256), dim3(256), 0, stream>>>(xproj_w_f, xprojB);
  dtwT_k<<<dim3(DTR * DI / 256), dim3(256), 0, stream>>>(dt_w_f, dtwT);
  chunk_k<<<dim3(NCHR, NB), dim3(THR), 0, stream>>>(
      x, W2T, b2, conv_w_f, conv_b_f, xprojB, dtwT, dt_b_f, A_log_f,
      sdt, Sb, clb, xclast, NCHR, LCr);
  fold_k<<<dim3((NB * DI) / 256), dim3(256), 0, stream>>>(
      sdt, Sb, A_log_f, clb, xclast, D_f, y, NCHR);
  tail_k<<<dim3(NB), dim3(512), 0, stream>>>(
      x, proj_w, proj_b, y, in_w_f, out_w_f, in_w_b, conv_w_b, conv_b_b,
      xproj_w_b, dt_w_b, dt_b_b, D_b, out_w_b, fusion_w, fusion_b, ln_g, ln_b,
      (float*)d_out);
}